// Round 11
// baseline (505.665 us; speedup 1.0000x reference)
//
#include <hip/hip_runtime.h>
#include <math.h>
#include <limits.h>

#define N_NODES 50000
#define N_EDGES 800000
#define N_GRAPHS 64
#define IN_CH 128
#define EMB 64
#define POOL_CHUNK 16   // 50000 = 16 * 3125 exactly
#define CPAD 32         // counts padded to one per 128B line
#define NSLICE 8        // channel slices; slice s -> XCD s via blockIdx%8 heuristic
#define SLICE_CH 8      // channels per slice (EMB / NSLICE); row = 32B = 2 x float4
#define AGG_NODES 16    // nodes per agg block (16 | 64 -> contiguous CSR range)
#define AGG_CAP 1024    // staged CSR entries (8 KB LDS); mean need ~256, std ~16

// ---------- init: padded counts=0, total=0, pool accumulators ----------
__global__ void init_k(int* counts, int* total, int* gmax, float* gsum, int* cnt) {
    int i = blockIdx.x * blockDim.x + threadIdx.x;
    if (i < N_NODES * CPAD) counts[i] = 0;
    if (i == 0) *total = 0;
    if (i < N_GRAPHS * EMB) { gmax[i] = INT_MIN; gsum[i] = 0.f; }
    if (i < N_GRAPHS) cnt[i] = 0;
}

// ---------- histogram: in-degree count; returned old value = stable slot ----------
__global__ void hist_k(const int* __restrict__ dst, int* counts,
                       int* __restrict__ slot_in) {
    int e = blockIdx.x * blockDim.x + threadIdx.x;
    if (e >= N_EDGES) return;
    slot_in[e] = atomicAdd(&counts[(size_t)dst[e] * CPAD], 1);
}

// ---------- CSR range allocation: wave-scan + one atomic per wave ----------
// ranges are contiguous+ascending within each 64-aligned node group
__global__ void alloc_k(const int* __restrict__ counts, int* __restrict__ row_start,
                        int* __restrict__ row_end, int* total) {
    int i = blockIdx.x * blockDim.x + threadIdx.x;
    int lane = threadIdx.x & 63;
    int c = (i < N_NODES) ? counts[(size_t)i * CPAD] : 0;
    int inc = c;
    for (int off = 1; off < 64; off <<= 1) {
        int v = __shfl_up(inc, off);
        if (lane >= off) inc += v;
    }
    int base;
    if (lane == 63) base = atomicAdd(total, inc);
    base = __shfl(base, 63);
    int excl = base + inc - c;
    if (i < N_NODES) { row_start[i] = excl; row_end[i] = excl + c; }
}

// ---------- scatter edges into CSR slots (atomic-free); store (src, raw w) ----------
__global__ void scatter_k(const int* __restrict__ src, const int* __restrict__ dst,
                          const float* __restrict__ w, const int* __restrict__ slot_in,
                          const int* __restrict__ row_start, int2* __restrict__ csr) {
    int e = blockIdx.x * blockDim.x + threadIdx.x;
    if (e >= N_EDGES) return;
    int d = dst[e];
    int slot = row_start[d] + slot_in[e];
    csr[slot] = make_int2(src[e], __float_as_int(w[e]));
}

// ---------- per-node weighted degree (wave reduction over CSR range) -> dinv ----------
__global__ __launch_bounds__(256) void deg_dinv_k(const int2* __restrict__ csr,
                                                  const int* __restrict__ row_start,
                                                  const int* __restrict__ row_end,
                                                  float* __restrict__ dinv) {
    int node = (blockIdx.x * blockDim.x + threadIdx.x) >> 6;
    int lane = threadIdx.x & 63;
    if (node >= N_NODES) return;
    int beg = row_start[node], end = row_end[node];
    float s = 0.f;
    for (int i = beg + lane; i < end; i += 64) s += __int_as_float(csr[i].y);
    for (int off = 32; off > 0; off >>= 1) s += __shfl_down(s, off);
    if (lane == 0) {
        float d = 1.0f + s;  // self-loop weight 1
        dinv[node] = d > 0.f ? rsqrtf(d) : 0.f;
    }
}

// ---------- rewrite csr.y: raw w -> norm = dinv[s] * w * dinv[d] ----------
__global__ __launch_bounds__(256) void normfix_k(int2* __restrict__ csr,
                                                 const int* __restrict__ row_start,
                                                 const int* __restrict__ row_end,
                                                 const float* __restrict__ dinv) {
    int node = (blockIdx.x * blockDim.x + threadIdx.x) >> 6;
    int lane = threadIdx.x & 63;
    if (node >= N_NODES) return;
    int beg = row_start[node], end = row_end[node];
    float dd = dinv[node];
    for (int i = beg + lane; i < end; i += 64) {
        int2 r = csr[i];
        float nm = dinv[r.x] * __int_as_float(r.y) * dd;
        csr[i] = make_int2(r.x, __float_as_int(nm));
    }
}

// ---------- layer-0 GEMM: standard-layout A (x), sliced-layout output T ----------
template<int K>
__global__ __launch_bounds__(256) void gemm_k(const float* __restrict__ A,
                                              const float* __restrict__ W,
                                              float* __restrict__ T) {
    __shared__ float Al[64 * K];
    __shared__ float Wl[K * EMB];
    int tid = threadIdx.x;
    long rowBase = (long)blockIdx.x * 64;
    int validRows = (int)min((long)64, (long)N_NODES - rowBase);

    const float4* Ag = (const float4*)(A + rowBase * K);
    for (int i = tid; i < validRows * (K / 4); i += 256) {
        int r = i / (K / 4), kc = i % (K / 4);
        float4 v = Ag[(long)r * (K / 4) + kc];
        *(float4*)&Al[r * K + 4 * (kc ^ (r & 3))] = v;
    }
    const float4* Wg = (const float4*)W;
    float4* Wl4 = (float4*)Wl;
    for (int i = tid; i < K * EMB / 4; i += 256) Wl4[i] = Wg[i];
    __syncthreads();

    int tc = tid & 15, tr = tid >> 4;
    int r0 = tr * 4, c0 = tc * 4;
    float acc[4][4] = {};
#pragma unroll 2
    for (int k = 0; k < K; k += 4) {
        int kc = k >> 2;
        float4 a[4], w[4];
#pragma unroll
        for (int i = 0; i < 4; ++i)
            a[i] = *(const float4*)&Al[(r0 + i) * K + 4 * (kc ^ i)];
#pragma unroll
        for (int j = 0; j < 4; ++j)
            w[j] = *(const float4*)&Wl[(k + j) * EMB + c0];
#pragma unroll
        for (int i = 0; i < 4; ++i) {
            const float* ai = (const float*)&a[i];
#pragma unroll
            for (int kk = 0; kk < 4; ++kk) {
                float av = ai[kk];
                const float* wk = (const float*)&w[kk];
#pragma unroll
                for (int j = 0; j < 4; ++j) acc[i][j] += av * wk[j];
            }
        }
    }
    long sliceOff = (long)(tc >> 1) * N_NODES * SLICE_CH + (c0 & 7);
#pragma unroll
    for (int i = 0; i < 4; ++i) {
        long row = rowBase + r0 + i;
        if (row < N_NODES)
            *(float4*)&T[sliceOff + row * SLICE_CH] =
                make_float4(acc[i][0], acc[i][1], acc[i][2], acc[i][3]);
    }
}

// ---------- layers 1-3 GEMM: sliced-layout A (S), sliced-layout output T ----------
__global__ __launch_bounds__(256) void gemm_sliced_k(const float* __restrict__ S,
                                                     const float* __restrict__ W,
                                                     float* __restrict__ T) {
    const int K = EMB;  // 64
    __shared__ float Al[64 * K];
    __shared__ float Wl[K * EMB];
    int tid = threadIdx.x;
    long rowBase = (long)blockIdx.x * 64;

    for (int i = tid; i < 64 * 16; i += 256) {
        int s = i >> 7;
        int r = (i & 127) >> 1, half = i & 1;
        long row = rowBase + r;
        if (row < N_NODES) {
            float4 v = *(const float4*)&S[(size_t)s * N_NODES * SLICE_CH +
                                          row * SLICE_CH + half * 4];
            int kc = s * 2 + half;
            *(float4*)&Al[r * K + 4 * (kc ^ (r & 3))] = v;
        }
    }
    const float4* Wg = (const float4*)W;
    float4* Wl4 = (float4*)Wl;
    for (int i = tid; i < K * EMB / 4; i += 256) Wl4[i] = Wg[i];
    __syncthreads();

    int tc = tid & 15, tr = tid >> 4;
    int r0 = tr * 4, c0 = tc * 4;
    float acc[4][4] = {};
#pragma unroll 2
    for (int k = 0; k < K; k += 4) {
        int kc = k >> 2;
        float4 a[4], w[4];
#pragma unroll
        for (int i = 0; i < 4; ++i)
            a[i] = *(const float4*)&Al[(r0 + i) * K + 4 * (kc ^ i)];
#pragma unroll
        for (int j = 0; j < 4; ++j)
            w[j] = *(const float4*)&Wl[(k + j) * EMB + c0];
#pragma unroll
        for (int i = 0; i < 4; ++i) {
            const float* ai = (const float*)&a[i];
#pragma unroll
            for (int kk = 0; kk < 4; ++kk) {
                float av = ai[kk];
                const float* wk = (const float*)&w[kk];
#pragma unroll
                for (int j = 0; j < 4; ++j) acc[i][j] += av * wk[j];
            }
        }
    }
    long sliceOff = (long)(tc >> 1) * N_NODES * SLICE_CH + (c0 & 7);
#pragma unroll
    for (int i = 0; i < 4; ++i) {
        long row = rowBase + r0 + i;
        if (row < N_NODES)
            *(float4*)&T[sliceOff + row * SLICE_CH] =
                make_float4(acc[i][0], acc[i][1], acc[i][2], acc[i][3]);
    }
}

// ---------- fused aggregation: XCD-sliced table + float4 gathers ----------
// slice = blockIdx%8 -> one XCD; 1.6MB slice L2-resident (proven: FETCH 116->35MB).
// Lane = (node g 0..15 via tid>>4, edge-slot s 0..7, half h 0..1). Each lane
// gathers a float4 (half a 32B slice row) -> one wave instr covers 32 edges
// (4x fewer vmem instrs than 4B/lane; vmem-instr issue is the measured bound).
// CSR from LDS (nt-staged, contiguous range since 16 | 64-aligned alloc groups).
// 3 xor-shuffle rounds reduce over slots; tanh+store in a packed phase-2.
__global__ __launch_bounds__(256) void fused_agg_k(const float* __restrict__ T,
                                                   const int2* __restrict__ csr,
                                                   const int* __restrict__ row_start,
                                                   const int* __restrict__ row_end,
                                                   const float* __restrict__ dinv,
                                                   const float* __restrict__ b,
                                                   float* __restrict__ S) {
    __shared__ int2 lcsr[AGG_CAP];
    __shared__ float sums[AGG_NODES][SLICE_CH];
    int slice = blockIdx.x & 7;
    int n0 = (blockIdx.x >> 3) * AGG_NODES;   // 3125*16 = 50000 exact
    int tid = threadIdx.x;
    int base = row_start[n0];
    int count = row_end[n0 + AGG_NODES - 1] - base;
    int stage = min(count, AGG_CAP);
    for (int i = tid; i < stage; i += 256) {
        long long p = __builtin_nontemporal_load((const long long*)&csr[base + i]);
        lcsr[i] = make_int2((int)(unsigned)(p & 0xffffffffLL), (int)(p >> 32));
    }
    __syncthreads();

    int g = tid >> 4;          // node within block
    int s = (tid >> 1) & 7;    // edge slot
    int h = tid & 1;           // which float4 of the 32B row
    int node = n0 + g;
    const float4* Ts4 = (const float4*)(T + (size_t)slice * N_NODES * SLICE_CH);
    int ls = row_start[node] - base;
    int le = row_end[node] - base;
    int leL = min(le, AGG_CAP);
    float4 acc = make_float4(0.f, 0.f, 0.f, 0.f);
    int l = ls + s;
    for (; l < leL; l += 8) {
        int2 r = lcsr[l];
        float nm = __int_as_float(r.y);
        float4 v = Ts4[(size_t)r.x * 2 + h];
        acc.x += nm * v.x; acc.y += nm * v.y;
        acc.z += nm * v.z; acc.w += nm * v.w;
    }
    for (; l < le; l += 8) {   // overflow fallback (statistically never)
        int2 r = csr[base + l];
        float nm = __int_as_float(r.y);
        float4 v = Ts4[(size_t)r.x * 2 + h];
        acc.x += nm * v.x; acc.y += nm * v.y;
        acc.z += nm * v.z; acc.w += nm * v.w;
    }
    // reduce over slot bits (lane bits 1..3; stays within 16-lane node group)
#pragma unroll
    for (int off = 2; off <= 8; off <<= 1) {
        acc.x += __shfl_xor(acc.x, off);
        acc.y += __shfl_xor(acc.y, off);
        acc.z += __shfl_xor(acc.z, off);
        acc.w += __shfl_xor(acc.w, off);
    }
    if (s == 0) {
        float di = dinv[node];
        float4 vs = Ts4[(size_t)node * 2 + h];
        float4 b4 = *(const float4*)&b[slice * SLICE_CH + h * 4];
        float d2 = di * di;
        float4 r4;
        r4.x = d2 * vs.x + b4.x + acc.x;
        r4.y = d2 * vs.y + b4.y + acc.y;
        r4.z = d2 * vs.z + b4.z + acc.z;
        r4.w = d2 * vs.w + b4.w + acc.w;
        *(float4*)&sums[g][h * 4] = r4;
    }
    __syncthreads();
    // packed epilogue: 128 threads do tanh + coalesced store
    if (tid < AGG_NODES * SLICE_CH) {
        int n = tid >> 3, c = tid & 7;
        S[(size_t)slice * N_NODES * SLICE_CH + (size_t)(n0 + n) * SLICE_CH + c] =
            tanhf(sums[n][c]);
    }
}

// ---------- pooling ----------
__device__ inline int f2ord(float x) {
    int bb = __float_as_int(x);
    return bb >= 0 ? bb : (bb ^ 0x7fffffff);
}
__device__ inline float ord2f(int k) {
    return __int_as_float(k >= 0 ? k : (k ^ 0x7fffffff));
}

// wave = 16 contiguous nodes (batch sorted); lane = channel; reads sliced S
// (channel mapping is identity: slice*8 + (lane&7) == lane).
__global__ __launch_bounds__(256) void pool_k(const float* __restrict__ S,
                                              const int* __restrict__ batch,
                                              int* gmax, float* gsum, int* cnt) {
    int wave = (blockIdx.x * blockDim.x + threadIdx.x) >> 6;
    int lane = threadIdx.x & 63;
    int start = wave * POOL_CHUNK;
    if (start >= N_NODES) return;
    size_t base = (size_t)(lane >> 3) * N_NODES * SLICE_CH + (lane & 7);
    int bsel = (lane < POOL_CHUNK) ? batch[start + lane] : 0;
    float v[POOL_CHUNK];
#pragma unroll
    for (int i = 0; i < POOL_CHUNK; ++i)
        v[i] = S[base + (size_t)(start + i) * SLICE_CH];
    int curg = __shfl(bsel, 0);
    float mx = -INFINITY, sm = 0.f;
    int ct = 0;
#pragma unroll
    for (int i = 0; i < POOL_CHUNK; ++i) {
        int g = __shfl(bsel, i);
        if (g != curg) {
            atomicMax(&gmax[curg * EMB + lane], f2ord(mx));
            atomicAdd(&gsum[curg * EMB + lane], sm);
            if (lane == 0) atomicAdd(&cnt[curg], ct);
            curg = g; mx = -INFINITY; sm = 0.f; ct = 0;
        }
        mx = fmaxf(mx, v[i]);
        sm += v[i];
        ++ct;
    }
    atomicMax(&gmax[curg * EMB + lane], f2ord(mx));
    atomicAdd(&gsum[curg * EMB + lane], sm);
    if (lane == 0) atomicAdd(&cnt[curg], ct);
}

__global__ void final_k(const int* __restrict__ gmax, const float* __restrict__ gsum,
                        const int* __restrict__ cnt, const float* __restrict__ Wout,
                        const float* __restrict__ bout, float* __restrict__ out) {
    int g = threadIdx.x;
    if (g >= N_GRAPHS) return;
    float c = fmaxf((float)cnt[g], 1.0f);
    float acc = bout[0];
    for (int ch = 0; ch < EMB; ++ch) {
        acc += ord2f(gmax[g * EMB + ch]) * Wout[ch]
             + (gsum[g * EMB + ch] / c) * Wout[EMB + ch];
    }
    out[g] = acc;
}

extern "C" void kernel_launch(void* const* d_in, const int* in_sizes, int n_in,
                              void* d_out, int out_size, void* d_ws, size_t ws_size,
                              hipStream_t stream) {
    const float* x         = (const float*)d_in[0];
    const int*   edge_idx  = (const int*)d_in[1];
    const float* edge_attr = (const float*)d_in[2];
    const int*   batch     = (const int*)d_in[3];
    const float* W0 = (const float*)d_in[4];
    const float* b0 = (const float*)d_in[5];
    const float* W1 = (const float*)d_in[6];
    const float* b1 = (const float*)d_in[7];
    const float* W2 = (const float*)d_in[8];
    const float* b2 = (const float*)d_in[9];
    const float* W3 = (const float*)d_in[10];
    const float* b3 = (const float*)d_in[11];
    const float* Wout = (const float*)d_in[12];
    const float* bout = (const float*)d_in[13];
    float* out = (float*)d_out;

    const int* src = edge_idx;            // edge_index[0]
    const int* dst = edge_idx + N_EDGES;  // edge_index[1]

    // workspace layout (~43 MB)
    char* ws = (char*)d_ws;
    float* dinv      = (float*)ws; ws += (size_t)N_NODES * sizeof(float);
    int*   counts    = (int*)ws;   ws += (size_t)N_NODES * CPAD * sizeof(int);
    int*   row_start = (int*)ws;   ws += (size_t)N_NODES * sizeof(int);
    int*   row_end   = (int*)ws;   ws += (size_t)N_NODES * sizeof(int);
    int*   slot_in   = (int*)ws;   ws += (size_t)N_EDGES * sizeof(int);
    int*   total     = (int*)ws;   ws += 4 * sizeof(int);  // keep 16B alignment
    int2*  csr       = (int2*)ws;  ws += (size_t)N_EDGES * sizeof(int2);
    float* T         = (float*)ws; ws += (size_t)N_NODES * EMB * sizeof(float);  // sliced gemm out
    float* S         = (float*)ws; ws += (size_t)N_NODES * EMB * sizeof(float);  // sliced agg out
    int*   gmax      = (int*)ws;   ws += N_GRAPHS * EMB * sizeof(int);
    float* gsum      = (float*)ws; ws += N_GRAPHS * EMB * sizeof(float);
    int*   cnt       = (int*)ws;   ws += N_GRAPHS * sizeof(int);

    const int nodeB = (N_NODES + 255) / 256;
    const int edgeB = (N_EDGES + 255) / 256;
    const int waveB = (N_NODES * 64 + 255) / 256;
    const int gemmB = (N_NODES + 63) / 64;
    const int initB = (N_NODES * CPAD + 255) / 256;
    const int aggB  = (N_NODES / AGG_NODES) * NSLICE;  // 3125 x 8 = 25000

    // CSR + norm precompute (shared by all 4 layers)
    init_k<<<initB, 256, 0, stream>>>(counts, total, gmax, gsum, cnt);
    hist_k<<<edgeB, 256, 0, stream>>>(dst, counts, slot_in);
    alloc_k<<<nodeB, 256, 0, stream>>>(counts, row_start, row_end, total);
    scatter_k<<<edgeB, 256, 0, stream>>>(src, dst, edge_attr, slot_in, row_start, csr);
    deg_dinv_k<<<waveB, 256, 0, stream>>>(csr, row_start, row_end, dinv);
    normfix_k<<<waveB, 256, 0, stream>>>(csr, row_start, row_end, dinv);

    const float* Wl[4] = {W0, W1, W2, W3};
    const float* bl[4] = {b0, b1, b2, b3};
    for (int l = 0; l < 4; ++l) {
        if (l == 0) gemm_k<IN_CH><<<gemmB, 256, 0, stream>>>(x, Wl[0], T);
        else        gemm_sliced_k<<<gemmB, 256, 0, stream>>>(S, Wl[l], T);
        fused_agg_k<<<aggB, 256, 0, stream>>>(T, csr, row_start, row_end, dinv, bl[l], S);
    }

    pool_k<<<(((N_NODES + POOL_CHUNK - 1) / POOL_CHUNK) * 64 + 255) / 256, 256, 0, stream>>>(
        S, batch, gmax, gsum, cnt);
    final_k<<<1, 64, 0, stream>>>(gmax, gsum, cnt, Wout, bout, out);
}

// Round 12
// 418.907 us; speedup vs baseline: 1.2071x; 1.2071x over previous
//
#include <hip/hip_runtime.h>
#include <math.h>
#include <limits.h>

#define N_NODES 50000
#define N_EDGES 800000
#define N_GRAPHS 64
#define IN_CH 128
#define EMB 64
#define POOL_CHUNK 16   // 50000 = 16 * 3125 exactly
#define CPAD 32         // counts padded to one per 128B line (atomic contention /32)

// ---------- init: padded counts=0, total=0, pool accumulators ----------
__global__ void init_k(int* counts, int* total, int* gmax, float* gsum, int* cnt) {
    int i = blockIdx.x * blockDim.x + threadIdx.x;
    if (i < N_NODES * CPAD) counts[i] = 0;
    if (i == 0) *total = 0;
    if (i < N_GRAPHS * EMB) { gmax[i] = INT_MIN; gsum[i] = 0.f; }
    if (i < N_GRAPHS) cnt[i] = 0;
}

// ---------- histogram: in-degree count; returned old value = stable slot ----------
__global__ void hist_k(const int* __restrict__ dst, int* counts,
                       int* __restrict__ slot_in) {
    int e = blockIdx.x * blockDim.x + threadIdx.x;
    if (e >= N_EDGES) return;
    slot_in[e] = atomicAdd(&counts[(size_t)dst[e] * CPAD], 1);
}

// ---------- CSR range allocation: wave-scan + one atomic per wave ----------
__global__ void alloc_k(const int* __restrict__ counts, int* __restrict__ row_start,
                        int* __restrict__ row_end, int* total) {
    int i = blockIdx.x * blockDim.x + threadIdx.x;
    int lane = threadIdx.x & 63;
    int c = (i < N_NODES) ? counts[(size_t)i * CPAD] : 0;
    int inc = c;
    for (int off = 1; off < 64; off <<= 1) {
        int v = __shfl_up(inc, off);
        if (lane >= off) inc += v;
    }
    int base;
    if (lane == 63) base = atomicAdd(total, inc);
    base = __shfl(base, 63);
    int excl = base + inc - c;
    if (i < N_NODES) { row_start[i] = excl; row_end[i] = excl + c; }
}

// ---------- scatter edges into CSR slots (atomic-free); store (src, raw w) ----------
__global__ void scatter_k(const int* __restrict__ src, const int* __restrict__ dst,
                          const float* __restrict__ w, const int* __restrict__ slot_in,
                          const int* __restrict__ row_start, int2* __restrict__ csr) {
    int e = blockIdx.x * blockDim.x + threadIdx.x;
    if (e >= N_EDGES) return;
    int d = dst[e];
    int slot = row_start[d] + slot_in[e];
    csr[slot] = make_int2(src[e], __float_as_int(w[e]));
}

// ---------- per-node weighted degree (wave reduction over CSR range) -> dinv ----------
__global__ __launch_bounds__(256) void deg_dinv_k(const int2* __restrict__ csr,
                                                  const int* __restrict__ row_start,
                                                  const int* __restrict__ row_end,
                                                  float* __restrict__ dinv) {
    int node = (blockIdx.x * blockDim.x + threadIdx.x) >> 6;
    int lane = threadIdx.x & 63;
    if (node >= N_NODES) return;
    int beg = row_start[node], end = row_end[node];
    float s = 0.f;
    for (int i = beg + lane; i < end; i += 64) s += __int_as_float(csr[i].y);
    for (int off = 32; off > 0; off >>= 1) s += __shfl_down(s, off);
    if (lane == 0) {
        float d = 1.0f + s;  // self-loop weight 1
        dinv[node] = d > 0.f ? rsqrtf(d) : 0.f;
    }
}

// ---------- rewrite csr.y: raw w -> norm = dinv[s] * w * dinv[d] ----------
__global__ __launch_bounds__(256) void normfix_k(int2* __restrict__ csr,
                                                 const int* __restrict__ row_start,
                                                 const int* __restrict__ row_end,
                                                 const float* __restrict__ dinv) {
    int node = (blockIdx.x * blockDim.x + threadIdx.x) >> 6;
    int lane = threadIdx.x & 63;
    if (node >= N_NODES) return;
    int beg = row_start[node], end = row_end[node];
    float dd = dinv[node];
    for (int i = beg + lane; i < end; i += 64) {
        int2 r = csr[i];
        float nm = dinv[r.x] * __int_as_float(r.y) * dd;
        csr[i] = make_int2(r.x, __float_as_int(nm));
    }
}

// ---------- h = A @ W : LDS-tiled, 64x64 output tile, 4x4 register tile ----------
template<int K>
__global__ __launch_bounds__(256) void gemm_k(const float* __restrict__ A,
                                              const float* __restrict__ W,
                                              float* __restrict__ out) {
    __shared__ float Al[64 * K];
    __shared__ float Wl[K * EMB];
    int tid = threadIdx.x;
    long rowBase = (long)blockIdx.x * 64;
    int validRows = (int)min((long)64, (long)N_NODES - rowBase);

    const float4* Ag = (const float4*)(A + rowBase * K);
    for (int i = tid; i < validRows * (K / 4); i += 256) {
        int r = i / (K / 4), kc = i % (K / 4);
        float4 v = Ag[(long)r * (K / 4) + kc];
        *(float4*)&Al[r * K + 4 * (kc ^ (r & 3))] = v;
    }
    const float4* Wg = (const float4*)W;
    float4* Wl4 = (float4*)Wl;
    for (int i = tid; i < K * EMB / 4; i += 256) Wl4[i] = Wg[i];
    __syncthreads();

    int tc = tid & 15, tr = tid >> 4;
    int r0 = tr * 4, c0 = tc * 4;
    float acc[4][4] = {};
#pragma unroll 2
    for (int k = 0; k < K; k += 4) {
        int kc = k >> 2;
        float4 a[4], w[4];
#pragma unroll
        for (int i = 0; i < 4; ++i)
            a[i] = *(const float4*)&Al[(r0 + i) * K + 4 * (kc ^ i)];
#pragma unroll
        for (int j = 0; j < 4; ++j)
            w[j] = *(const float4*)&Wl[(k + j) * EMB + c0];
#pragma unroll
        for (int i = 0; i < 4; ++i) {
            const float* ai = (const float*)&a[i];
#pragma unroll
            for (int kk = 0; kk < 4; ++kk) {
                float av = ai[kk];
                const float* wk = (const float*)&w[kk];
#pragma unroll
                for (int j = 0; j < 4; ++j) acc[i][j] += av * wk[j];
            }
        }
    }
#pragma unroll
    for (int i = 0; i < 4; ++i) {
        long row = rowBase + r0 + i;
        if (row < N_NODES)
            *(float4*)&out[row * EMB + c0] =
                make_float4(acc[i][0], acc[i][1], acc[i][2], acc[i][3]);
    }
}

// ---------- fused aggregation: self-loop + bias + CSR gather + tanh ----------
// one wave per node; lane = channel; 8 gathers in flight. Each gather wave-
// instruction covers one full 256B row = 4 fully-utilized cache lines -- the
// measured per-CU line-request throughput (~8cyc/line) makes this the optimal
// fp32 layout (R8-R11 restructures all regressed; see journal).
__global__ __launch_bounds__(256) void fused_agg_k(const float* __restrict__ h,
                                                   const int2* __restrict__ csr,
                                                   const int* __restrict__ row_start,
                                                   const int* __restrict__ row_end,
                                                   const float* __restrict__ dinv,
                                                   const float* __restrict__ b,
                                                   float* __restrict__ out) {
    int node = (blockIdx.x * blockDim.x + threadIdx.x) >> 6;
    int lane = threadIdx.x & 63;
    if (node >= N_NODES) return;
    float di = dinv[node];
    float acc = di * di * h[(long)node * EMB + lane] + b[lane];
    int e = row_start[node];
    int end = row_end[node];
    for (; e + 7 < end; e += 8) {
        int2 r[8];
        float v[8];
#pragma unroll
        for (int i = 0; i < 8; ++i) r[i] = csr[e + i];
#pragma unroll
        for (int i = 0; i < 8; ++i) v[i] = h[(long)r[i].x * EMB + lane];
#pragma unroll
        for (int i = 0; i < 8; ++i) acc += __int_as_float(r[i].y) * v[i];
    }
    for (; e + 3 < end; e += 4) {
        int2 r0 = csr[e], r1 = csr[e + 1], r2 = csr[e + 2], r3 = csr[e + 3];
        float v0 = h[(long)r0.x * EMB + lane];
        float v1 = h[(long)r1.x * EMB + lane];
        float v2 = h[(long)r2.x * EMB + lane];
        float v3 = h[(long)r3.x * EMB + lane];
        acc += __int_as_float(r0.y) * v0;
        acc += __int_as_float(r1.y) * v1;
        acc += __int_as_float(r2.y) * v2;
        acc += __int_as_float(r3.y) * v3;
    }
    for (; e < end; ++e) {
        int2 r0 = csr[e];
        acc += __int_as_float(r0.y) * h[(long)r0.x * EMB + lane];
    }
    __builtin_nontemporal_store(tanhf(acc), &out[(long)node * EMB + lane]);
}

// ---------- pooling ----------
__device__ inline int f2ord(float x) {
    int bb = __float_as_int(x);
    return bb >= 0 ? bb : (bb ^ 0x7fffffff);
}
__device__ inline float ord2f(int k) {
    return __int_as_float(k >= 0 ? k : (k ^ 0x7fffffff));
}

// wave = 16 contiguous nodes (batch sorted); lane = channel.
__global__ __launch_bounds__(256) void pool_k(const float* __restrict__ h,
                                              const int* __restrict__ batch,
                                              int* gmax, float* gsum, int* cnt) {
    int wave = (blockIdx.x * blockDim.x + threadIdx.x) >> 6;
    int lane = threadIdx.x & 63;
    int start = wave * POOL_CHUNK;
    if (start >= N_NODES) return;   // 50000 % 16 == 0 -> full chunks always
    int bsel = (lane < POOL_CHUNK) ? batch[start + lane] : 0;
    float v[POOL_CHUNK];
#pragma unroll
    for (int i = 0; i < POOL_CHUNK; ++i)
        v[i] = h[(long)(start + i) * EMB + lane];
    int curg = __shfl(bsel, 0);
    float mx = -INFINITY, sm = 0.f;
    int ct = 0;
#pragma unroll
    for (int i = 0; i < POOL_CHUNK; ++i) {
        int g = __shfl(bsel, i);
        if (g != curg) {
            atomicMax(&gmax[curg * EMB + lane], f2ord(mx));
            atomicAdd(&gsum[curg * EMB + lane], sm);
            if (lane == 0) atomicAdd(&cnt[curg], ct);
            curg = g; mx = -INFINITY; sm = 0.f; ct = 0;
        }
        mx = fmaxf(mx, v[i]);
        sm += v[i];
        ++ct;
    }
    atomicMax(&gmax[curg * EMB + lane], f2ord(mx));
    atomicAdd(&gsum[curg * EMB + lane], sm);
    if (lane == 0) atomicAdd(&cnt[curg], ct);
}

__global__ void final_k(const int* __restrict__ gmax, const float* __restrict__ gsum,
                        const int* __restrict__ cnt, const float* __restrict__ Wout,
                        const float* __restrict__ bout, float* __restrict__ out) {
    int g = threadIdx.x;
    if (g >= N_GRAPHS) return;
    float c = fmaxf((float)cnt[g], 1.0f);
    float acc = bout[0];
    for (int ch = 0; ch < EMB; ++ch) {
        acc += ord2f(gmax[g * EMB + ch]) * Wout[ch]
             + (gsum[g * EMB + ch] / c) * Wout[EMB + ch];
    }
    out[g] = acc;
}

extern "C" void kernel_launch(void* const* d_in, const int* in_sizes, int n_in,
                              void* d_out, int out_size, void* d_ws, size_t ws_size,
                              hipStream_t stream) {
    const float* x         = (const float*)d_in[0];
    const int*   edge_idx  = (const int*)d_in[1];
    const float* edge_attr = (const float*)d_in[2];
    const int*   batch     = (const int*)d_in[3];
    const float* W0 = (const float*)d_in[4];
    const float* b0 = (const float*)d_in[5];
    const float* W1 = (const float*)d_in[6];
    const float* b1 = (const float*)d_in[7];
    const float* W2 = (const float*)d_in[8];
    const float* b2 = (const float*)d_in[9];
    const float* W3 = (const float*)d_in[10];
    const float* b3 = (const float*)d_in[11];
    const float* Wout = (const float*)d_in[12];
    const float* bout = (const float*)d_in[13];
    float* out = (float*)d_out;

    const int* src = edge_idx;            // edge_index[0]
    const int* dst = edge_idx + N_EDGES;  // edge_index[1]

    // workspace layout (~43 MB)
    char* ws = (char*)d_ws;
    float* dinv      = (float*)ws; ws += (size_t)N_NODES * sizeof(float);
    int*   counts    = (int*)ws;   ws += (size_t)N_NODES * CPAD * sizeof(int);
    int*   row_start = (int*)ws;   ws += (size_t)N_NODES * sizeof(int);
    int*   row_end   = (int*)ws;   ws += (size_t)N_NODES * sizeof(int);
    int*   slot_in   = (int*)ws;   ws += (size_t)N_EDGES * sizeof(int);
    int*   total     = (int*)ws;   ws += 4 * sizeof(int);  // keep 16B alignment
    int2*  csr       = (int2*)ws;  ws += (size_t)N_EDGES * sizeof(int2);
    float* bufL      = (float*)ws; ws += (size_t)N_NODES * EMB * sizeof(float);
    float* bufH      = (float*)ws; ws += (size_t)N_NODES * EMB * sizeof(float);
    int*   gmax      = (int*)ws;   ws += N_GRAPHS * EMB * sizeof(int);
    float* gsum      = (float*)ws; ws += N_GRAPHS * EMB * sizeof(float);
    int*   cnt       = (int*)ws;   ws += N_GRAPHS * sizeof(int);

    const int nodeB = (N_NODES + 255) / 256;
    const int edgeB = (N_EDGES + 255) / 256;
    const int waveB = (N_NODES * 64 + 255) / 256;  // one wave per node
    const int gemmB = (N_NODES + 63) / 64;         // 782 blocks, 64-row tiles
    const int initB = (N_NODES * CPAD + 255) / 256;

    // CSR + norm precompute (shared by all 4 layers)
    init_k<<<initB, 256, 0, stream>>>(counts, total, gmax, gsum, cnt);
    hist_k<<<edgeB, 256, 0, stream>>>(dst, counts, slot_in);
    alloc_k<<<nodeB, 256, 0, stream>>>(counts, row_start, row_end, total);
    scatter_k<<<edgeB, 256, 0, stream>>>(src, dst, edge_attr, slot_in, row_start, csr);
    deg_dinv_k<<<waveB, 256, 0, stream>>>(csr, row_start, row_end, dinv);
    normfix_k<<<waveB, 256, 0, stream>>>(csr, row_start, row_end, dinv);

    const float* Wl[4] = {W0, W1, W2, W3};
    const float* bl[4] = {b0, b1, b2, b3};
    for (int l = 0; l < 4; ++l) {
        if (l == 0) gemm_k<IN_CH><<<gemmB, 256, 0, stream>>>(x, Wl[0], bufL);
        else        gemm_k<EMB>  <<<gemmB, 256, 0, stream>>>(bufH, Wl[l], bufL);
        fused_agg_k<<<waveB, 256, 0, stream>>>(bufL, csr, row_start, row_end, dinv, bl[l], bufH);
    }

    pool_k<<<(((N_NODES + POOL_CHUNK - 1) / POOL_CHUNK) * 64 + 255) / 256, 256, 0, stream>>>(
        bufH, batch, gmax, gsum, cnt);
    final_k<<<1, 64, 0, stream>>>(gmax, gsum, cnt, Wout, bout, out);
}